// Round 2
// 526.532 us; speedup vs baseline: 1.0420x; 1.0420x over previous
//
#include <hip/hip_runtime.h>
#include <hip/hip_bf16.h>

// Problem constants (N, K, C, CL, H fixed by the reference)
constexpr int Nn  = 1024;
constexpr int Kk  = 32;
constexpr int Cc  = 64;
constexpr int CLl = 128;

typedef unsigned int   u32;
typedef unsigned short u16;
typedef float f4v __attribute__((ext_vector_type(4)));

__device__ __forceinline__ float gelu_tanh(float v){
  float c = 0.7978845608028654f*(v + 0.044715f*v*v*v);
  return 0.5f*v*(1.f + tanhf(c));
}
__device__ __forceinline__ float bflo(u32 u){ return __uint_as_float(u<<16); }
__device__ __forceinline__ float bfhi(u32 u){ return __uint_as_float(u & 0xffff0000u); }
__device__ __forceinline__ u32 pack_bf(float a, float b){
  u32 xa = __float_as_uint(a), xb = __float_as_uint(b);
  u32 ra = (xa + 0x7fffu + ((xa>>16)&1u)) >> 16;
  u32 rb = (xb + 0x7fffu + ((xb>>16)&1u)) >> 16;
  return ra | (rb<<16);
}

// ---------------------------------------------------------------------------
// K0: A = local@Wa, B = local@Wb, inter = local@W_int + b_int  (all [N,64] f32)
// ---------------------------------------------------------------------------
__global__ __launch_bounds__(64) void k0(
    const float* __restrict__ local, const float* __restrict__ Wa,
    const float* __restrict__ Wb, const float* __restrict__ Wint,
    const float* __restrict__ b_int,
    float* __restrict__ A, float* __restrict__ B, float* __restrict__ inter){
  int i = blockIdx.x;
  int c = threadIdx.x;              // 0..63
  __shared__ float l[CLl];
  l[c]      = local[i*CLl + c];
  l[c + 64] = local[i*CLl + 64 + c];
  __syncthreads();
  float a = 0.f, b = 0.f, t = 0.f;
  #pragma unroll 4
  for(int d = 0; d < CLl; ++d){
    float ld = l[d];
    a = fmaf(ld, Wa[d*Cc + c], a);
    b = fmaf(ld, Wb[d*Cc + c], b);
    t = fmaf(ld, Wint[d*Cc + c], t);
  }
  A[i*Cc + c] = a;
  B[i*Cc + c] = b;
  inter[i*Cc + c] = t + b_int[c];
}

// ---------------------------------------------------------------------------
// K1: r1023[k][x] = (lp_row1023 @ W_right + b_right)[x],  qpart[k]
// ---------------------------------------------------------------------------
__global__ __launch_bounds__(256) void k1(
    const float* __restrict__ pair, const float* __restrict__ pair_update,
    const int* __restrict__ neigh, const int* __restrict__ mask,
    const float* __restrict__ ln_g, const float* __restrict__ ln_b,
    const float* __restrict__ W_aug, const float* __restrict__ W_right,
    const float* __restrict__ b_right,
    const float* __restrict__ A, const float* __restrict__ B,
    float* __restrict__ r1023, int* __restrict__ qpart){
  const int i = Nn - 1;
  __shared__ float wA[4096];
  __shared__ float wR[2048];
  __shared__ float p [Kk][68];
  __shared__ float pu[Kk][68];
  __shared__ float lp[Kk][68];
  __shared__ int   nwS[Kk];
  __shared__ float ssum[Kk][9], ssq[Kk][9], stats[Kk][2];
  int tid = threadIdx.x;
  for(int idx = tid; idx < 4096; idx += 256) wA[idx] = W_aug[idx];
  for(int idx = tid; idx < 2048; idx += 256) wR[idx] = W_right[idx];
  if(tid < Kk){
    int n = neigh[i*Kk + tid];
    nwS[tid] = (n < 0) ? n + Nn : n;
    qpart[tid] = (n != -1 && mask[n] != 0) ? 1 : 0;
  }
  __syncthreads();
  int k = tid >> 3, s = tid & 7;
  {
    const float* prow = pair + ((size_t)i*Nn + nwS[k])*Cc + s*8;
    const float* pur  = pair_update + ((size_t)i*Kk + k)*Cc + s*8;
    const float* Ar = A + i*Cc + s*8;
    const float* Br = B + (size_t)nwS[k]*Cc + s*8;
    float ps = 0.f, ps2 = 0.f;
    for(int j = 0; j < 8; ++j){
      float v = prow[j];
      p[k][s*8 + j] = v; ps += v; ps2 += v*v;
      pu[k][s*8 + j] = pur[j] + Ar[j] + Br[j];
    }
    ssum[k][s] = ps; ssq[k][s] = ps2;
  }
  __syncthreads();
  if(s == 0){
    float m = 0.f, q = 0.f;
    for(int j = 0; j < 8; ++j){ m += ssum[k][j]; q += ssq[k][j]; }
    m *= (1.f/64.f); q *= (1.f/64.f);
    float var = fmaxf(q - m*m, 0.f);
    stats[k][0] = m; stats[k][1] = rsqrtf(var + 1e-5f);
  }
  __syncthreads();
  {
    float m = stats[k][0], r = stats[k][1];
    float acc[8];
    #pragma unroll
    for(int j = 0; j < 8; ++j){
      int c = s*8 + j;
      acc[j] = (p[k][c] - m)*r*ln_g[c] + ln_b[c];
    }
    for(int d = 0; d < 64; ++d){
      float pd = pu[k][d];
      #pragma unroll
      for(int j = 0; j < 8; ++j) acc[j] = fmaf(pd, wA[d*64 + s*8 + j], acc[j]);
    }
    #pragma unroll
    for(int j = 0; j < 8; ++j) lp[k][s*8 + j] = acc[j];
  }
  __syncthreads();
  {
    float acc[4] = {0.f,0.f,0.f,0.f};
    for(int d = 0; d < 64; ++d){
      float ld = lp[k][d];
      #pragma unroll
      for(int j = 0; j < 4; ++j) acc[j] = fmaf(ld, wR[d*32 + s*4 + j], acc[j]);
    }
    #pragma unroll
    for(int j = 0; j < 4; ++j)
      r1023[k*32 + s*4 + j] = acc[j] + b_right[s*4 + j];
  }
}

// ---------------------------------------------------------------------------
// KBIG: merged k2a + kfuse. Per row i (grid 1024, 256 threads):
//   - row copy out[i,:] = pair[i,:] split into 3 chunks interleaved between
//     compute phases (copy BW drains under compute / barrier waits)
//   - gather + LN + lp = LN*g+b + pu@W_aug (pu bf16-packed in LDS)
//   - lin = lp@W_lin + inter (kept in REGISTERS), h = lp@W_left+b_left+r1023
//     (h kept in LDS; no hG/linG global round-trip)
//   - V = gelu(h@W1)@W2 via wave shuffles; contrib = mul*V + lin -> cbuf
//   - leader dedup-aggregate, overwrite touched columns
// LDS = 62.8 KiB (pbuf aliased as cbuf; LN scratch aliased as hbuf) -> 2 blk/CU
// ---------------------------------------------------------------------------
__global__ __launch_bounds__(256) void kbig(
    const float* __restrict__ pair, const float* __restrict__ pair_update,
    const int* __restrict__ neigh,
    const float* __restrict__ ln_g, const float* __restrict__ ln_b,
    const float* __restrict__ W_aug, const float* __restrict__ W_lin,
    const float* __restrict__ W_left, const float* __restrict__ b_left,
    const float* __restrict__ W1, const float* __restrict__ W2,
    const float* __restrict__ A, const float* __restrict__ B,
    const float* __restrict__ inter, const float* __restrict__ r1023,
    const int* __restrict__ qpart,
    float* __restrict__ out){

  __shared__ u32 wbA[2048];           // W_aug  [64][64] bf16-packed      8 KiB
  __shared__ u32 wbL[2048];           // W_lin  [64][64] bf16-packed      8 KiB
  __shared__ u32 wbF[1024];           // W_left [64][32] bf16-packed      4 KiB
  __shared__ u32 w1b[2048];           // W1 [32][128]   bf16-packed      8 KiB
  __shared__ u32 w2b[4096];           // W2 [128][64]   bf16-packed     16 KiB
  __shared__ float pbuf[Kk][68];      // raw p -> lp -> cbuf (contrib)  8.5 KiB
  __shared__ u32  puP [Kk][34];       // pu, bf16 pairs                4.25 KiB
  __shared__ float uA[1088];          // ssum/ssq then hbuf[32][34]    4.25 KiB
  __shared__ float stats[Kk][2];
  __shared__ float AiS[64], InS[64], lgS[64], lbS[64];
  __shared__ int nbS[Kk], nwS[Kk], quS[Kk], leadS[Kk];
  __shared__ int cminus;

  float* ssum = uA;                   // [32][9]  (dead after LN stats)
  float* ssq  = uA + 288;             // [32][9]
  float* hbuf = uA;                   // [32][34] (written in phase D)

  const int i   = blockIdx.x;
  const int tid = threadIdx.x;

  const f4v* __restrict__ srcRow = (const f4v*)(pair + (size_t)i*Nn*Cc);
  f4v* __restrict__       dstRow = (f4v*)(out + (size_t)i*Nn*Cc);

  // ---- copy chunk A: iters 0..31 (drains at B1 while other block computes) --
  #pragma unroll 4
  for(int it = 0; it < 32; ++it){
    int idx = it*256 + tid;
    dstRow[idx] = srcRow[idx];
  }

  // ---- stage all weights once (pack f32 -> bf16 pairs) ----
  for(int idx = tid; idx < 2048; idx += 256){
    const float2 wa = *(const float2*)(W_aug + idx*2);
    wbA[idx] = pack_bf(wa.x, wa.y);
    const float2 wl = *(const float2*)(W_lin + idx*2);
    wbL[idx] = pack_bf(wl.x, wl.y);
    const float2 w1 = *(const float2*)(W1 + idx*2);
    w1b[idx] = pack_bf(w1.x, w1.y);
    const float2 w2a = *(const float2*)(W2 + idx*2);
    w2b[idx] = pack_bf(w2a.x, w2a.y);
    const float2 w2c = *(const float2*)(W2 + 4096 + idx*2);
    w2b[2048 + idx] = pack_bf(w2c.x, w2c.y);
  }
  for(int idx = tid; idx < 1024; idx += 256){
    const float2 wf = *(const float2*)(W_left + idx*2);
    wbF[idx] = pack_bf(wf.x, wf.y);
  }
  if(tid < Kk){
    int n = neigh[i*Kk + tid];
    nbS[tid] = n;
    nwS[tid] = (n < 0) ? n + Nn : n;
    quS[tid] = qpart[tid];
  }
  if(tid < 64){
    AiS[tid] = A[i*Cc + tid];
    InS[tid] = inter[i*Cc + tid];
    lgS[tid] = ln_g[tid];
    lbS[tid] = ln_b[tid];
  }
  __syncthreads();                                   // B1

  if(tid == 0){
    int c = 0;
    for(int kk = 0; kk < Kk; ++kk) c |= (nbS[kk] == -1);
    cminus = c;
  }
  if(tid < Kk){
    int lead = 1;
    for(int kk = 0; kk < tid; ++kk) if(nwS[kk] == nwS[tid]) lead = 0;
    leadS[tid] = lead;
  }

  // ---- gather pair row segments + build pu (k8 = tid>>3, s8 = tid&7) ----
  {
    int k8 = tid >> 3, s8 = tid & 7;
    const float4* p4 = (const float4*)(pair + ((size_t)i*Nn + nwS[k8])*Cc) + s8*2;
    float4 p0 = p4[0], p1 = p4[1];
    const float4* u4 = (const float4*)(pair_update + ((size_t)i*Kk + k8)*Cc) + s8*2;
    float4 u0 = u4[0], u1 = u4[1];
    const float4* Br = (const float4*)(B + (size_t)nwS[k8]*Cc) + s8*2;
    float4 b0 = Br[0], b1 = Br[1];
    float pf[8] = {p0.x,p0.y,p0.z,p0.w,p1.x,p1.y,p1.z,p1.w};
    float uf[8] = {u0.x,u0.y,u0.z,u0.w,u1.x,u1.y,u1.z,u1.w};
    float bv[8] = {b0.x,b0.y,b0.z,b0.w,b1.x,b1.y,b1.z,b1.w};
    float ps = 0.f, ps2 = 0.f;
    #pragma unroll
    for(int j = 0; j < 8; ++j){
      float v = pf[j];
      pbuf[k8][s8*8 + j] = v; ps += v; ps2 += v*v;
    }
    #pragma unroll
    for(int j = 0; j < 4; ++j){
      float e0 = uf[2*j]   + AiS[s8*8 + 2*j]   + bv[2*j];
      float e1 = uf[2*j+1] + AiS[s8*8 + 2*j+1] + bv[2*j+1];
      puP[k8][s8*4 + j] = pack_bf(e0, e1);
    }
    ssum[k8*9 + s8] = ps; ssq[k8*9 + s8] = ps2;
  }
  __syncthreads();                                   // B2

  // ---- LN stats ----
  if((tid & 7) == 0){
    int k8 = tid >> 3;
    float m = 0.f, q = 0.f;
    for(int j = 0; j < 8; ++j){ m += ssum[k8*9 + j]; q += ssq[k8*9 + j]; }
    m *= (1.f/64.f); q *= (1.f/64.f);
    float var = fmaxf(q - m*m, 0.f);
    stats[k8][0] = m; stats[k8][1] = rsqrtf(var + 1e-5f);
  }
  __syncthreads();                                   // B3

  const int kq  = tid >> 4;          // 0..15 -> slots kq, kq+16
  const int s   = tid & 15;          // col group: c0 = s*4
  const int k0i = kq, k1i = kq + 16;
  const int c0  = s*4;

  // ---- phase C: lp = LN(pair)*g+b + pu @ W_aug ----
  float a0[4], a1[4];
  {
    float m0 = stats[k0i][0], r0 = stats[k0i][1];
    float m1 = stats[k1i][0], r1 = stats[k1i][1];
    #pragma unroll
    for(int j = 0; j < 4; ++j){
      int c = c0 + j;
      a0[j] = (pbuf[k0i][c] - m0)*r0*lgS[c] + lbS[c];
      a1[j] = (pbuf[k1i][c] - m1)*r1*lgS[c] + lbS[c];
    }
    #pragma unroll 2
    for(int dp = 0; dp < 32; ++dp){
      u32 q0 = puP[k0i][dp], q1 = puP[k1i][dp];
      float pe0 = bflo(q0), po0 = bfhi(q0);
      float pe1 = bflo(q1), po1 = bfhi(q1);
      uint2 we = *(const uint2*)&wbA[(2*dp)*32 + s*2];
      uint2 wo = *(const uint2*)&wbA[(2*dp+1)*32 + s*2];
      float w0 = bflo(we.x), w1 = bfhi(we.x), w2 = bflo(we.y), w3 = bfhi(we.y);
      a0[0] = fmaf(pe0, w0, a0[0]); a0[1] = fmaf(pe0, w1, a0[1]);
      a0[2] = fmaf(pe0, w2, a0[2]); a0[3] = fmaf(pe0, w3, a0[3]);
      a1[0] = fmaf(pe1, w0, a1[0]); a1[1] = fmaf(pe1, w1, a1[1]);
      a1[2] = fmaf(pe1, w2, a1[2]); a1[3] = fmaf(pe1, w3, a1[3]);
      float x0w = bflo(wo.x), x1w = bfhi(wo.x), x2w = bflo(wo.y), x3w = bfhi(wo.y);
      a0[0] = fmaf(po0, x0w, a0[0]); a0[1] = fmaf(po0, x1w, a0[1]);
      a0[2] = fmaf(po0, x2w, a0[2]); a0[3] = fmaf(po0, x3w, a0[3]);
      a1[0] = fmaf(po1, x0w, a1[0]); a1[1] = fmaf(po1, x1w, a1[1]);
      a1[2] = fmaf(po1, x2w, a1[2]); a1[3] = fmaf(po1, x3w, a1[3]);
    }
  }
  __syncthreads();                                   // B4 (raw p fully consumed)
  #pragma unroll
  for(int j = 0; j < 4; ++j){ pbuf[k0i][c0 + j] = a0[j]; pbuf[k1i][c0 + j] = a1[j]; }

  // ---- copy chunk B: iters 32..47 ----
  #pragma unroll 4
  for(int it = 32; it < 48; ++it){
    int idx = it*256 + tid;
    dstRow[idx] = srcRow[idx];
  }
  __syncthreads();                                   // B5 (lp visible)

  // ---- phase D: lin (regs) + h (LDS) ----
  float L0[4], L1[4];
  {
    float Lx0[4] = {0,0,0,0}, Lx1[4] = {0,0,0,0};
    float X0[2] = {0,0}, X1[2] = {0,0};
    #pragma unroll 4
    for(int d = 0; d < 64; ++d){
      float p0 = pbuf[k0i][d], p1 = pbuf[k1i][d];
      uint2 wv = *(const uint2*)&wbL[d*32 + s*2];
      float w0 = bflo(wv.x), w1 = bfhi(wv.x), w2 = bflo(wv.y), w3 = bfhi(wv.y);
      Lx0[0] = fmaf(p0, w0, Lx0[0]); Lx0[1] = fmaf(p0, w1, Lx0[1]);
      Lx0[2] = fmaf(p0, w2, Lx0[2]); Lx0[3] = fmaf(p0, w3, Lx0[3]);
      Lx1[0] = fmaf(p1, w0, Lx1[0]); Lx1[1] = fmaf(p1, w1, Lx1[1]);
      Lx1[2] = fmaf(p1, w2, Lx1[2]); Lx1[3] = fmaf(p1, w3, Lx1[3]);
      u32 wf = wbF[d*16 + s];
      float f0 = bflo(wf), f1 = bfhi(wf);
      X0[0] = fmaf(p0, f0, X0[0]); X0[1] = fmaf(p0, f1, X0[1]);
      X1[0] = fmaf(p1, f0, X1[0]); X1[1] = fmaf(p1, f1, X1[1]);
    }
    #pragma unroll
    for(int j = 0; j < 4; ++j){
      L0[j] = Lx0[j] + InS[c0 + j];
      L1[j] = Lx1[j] + InS[c0 + j];
    }
    int x0 = s*2;
    float2 bl = *(const float2*)(b_left + x0);
    float2 rA = *(const float2*)(r1023 + k0i*32 + x0);
    float2 rB = *(const float2*)(r1023 + k1i*32 + x0);
    hbuf[k0i*34 + x0]     = X0[0] + bl.x + rA.x;
    hbuf[k0i*34 + x0 + 1] = X0[1] + bl.y + rA.y;
    hbuf[k1i*34 + x0]     = X1[0] + bl.x + rB.x;
    hbuf[k1i*34 + x0 + 1] = X1[1] + bl.y + rB.y;
  }
  // ---- copy chunk C: iters 48..63 ----
  #pragma unroll 4
  for(int it = 48; it < 64; ++it){
    int idx = it*256 + tid;
    dstRow[idx] = srcRow[idx];
  }
  __syncthreads();                                   // B6 (h visible; copy done)

  // ---- phase E: g1 = gelu(h @ W1); V = g1 @ W2 via wave shuffles ----
  float g0[8], g1v[8];
  {
    float A0[8] = {0,0,0,0,0,0,0,0}, A1[8] = {0,0,0,0,0,0,0,0};
    #pragma unroll 2
    for(int x = 0; x < 32; ++x){
      float h0 = hbuf[k0i*34 + x], h1 = hbuf[k1i*34 + x];
      uint4 wv = *(const uint4*)&w1b[x*64 + s*4];
      float w[8] = {bflo(wv.x),bfhi(wv.x),bflo(wv.y),bfhi(wv.y),
                    bflo(wv.z),bfhi(wv.z),bflo(wv.w),bfhi(wv.w)};
      #pragma unroll
      for(int j = 0; j < 8; ++j){
        A0[j] = fmaf(h0, w[j], A0[j]);
        A1[j] = fmaf(h1, w[j], A1[j]);
      }
    }
    #pragma unroll
    for(int j = 0; j < 8; ++j){ g0[j] = gelu_tanh(A0[j]); g1v[j] = gelu_tanh(A1[j]); }
  }
  {
    float V0[4] = {0,0,0,0}, V1[4] = {0,0,0,0};
    int lbase = (kq & 3) << 4;       // lane block of this kq within the wave
    for(int hb = 0; hb < 16; ++hb){
      int srcl = lbase | hb;         // lane holding h-cols hb*8..hb*8+7
      #pragma unroll
      for(int hj = 0; hj < 8; ++hj){
        float gA = __shfl(g0[hj],  srcl, 64);
        float gB = __shfl(g1v[hj], srcl, 64);
        int h = hb*8 + hj;
        uint2 wv = *(const uint2*)&w2b[h*32 + s*2];
        float w0 = bflo(wv.x), w1 = bfhi(wv.x), w2 = bflo(wv.y), w3 = bfhi(wv.y);
        V0[0] = fmaf(gA, w0, V0[0]); V0[1] = fmaf(gA, w1, V0[1]);
        V0[2] = fmaf(gA, w2, V0[2]); V0[3] = fmaf(gA, w3, V0[3]);
        V1[0] = fmaf(gB, w0, V1[0]); V1[1] = fmaf(gB, w1, V1[1]);
        V1[2] = fmaf(gB, w2, V1[2]); V1[3] = fmaf(gB, w3, V1[3]);
      }
    }
    float mul0 = (cminus && quS[k0i] && nbS[k0i] != -1) ? 1.f : 0.f;
    float mul1 = (cminus && quS[k1i] && nbS[k1i] != -1) ? 1.f : 0.f;
    // contrib -> pbuf (lp is dead past B6; pbuf doubles as cbuf)
    #pragma unroll
    for(int j = 0; j < 4; ++j){
      pbuf[k0i][c0 + j] = fmaf(mul0, V0[j], L0[j]);
      pbuf[k1i][c0 + j] = fmaf(mul1, V1[j], L1[j]);
    }
  }
  __syncthreads();                                   // B7

  // ---- leader dedup + aggregate + overwrite touched columns ----
  {
    int k8 = tid >> 3, s8 = tid & 7;
    if(leadS[k8]){
      int col = nwS[k8];
      float tot[8] = {0,0,0,0,0,0,0,0};
      for(int kk = 0; kk < Kk; ++kk){
        if(nwS[kk] == col){
          #pragma unroll
          for(int j = 0; j < 8; ++j) tot[j] += pbuf[kk][s8*8 + j];
        }
      }
      size_t base = ((size_t)i*Nn + col)*Cc + s8*8;
      const float4* pv = (const float4*)(pair + base);
      float4 p0 = pv[0], p1 = pv[1];
      float4 o0 = make_float4(p0.x+tot[0], p0.y+tot[1], p0.z+tot[2], p0.w+tot[3]);
      float4 o1 = make_float4(p1.x+tot[4], p1.y+tot[5], p1.z+tot[6], p1.w+tot[7]);
      float4* ov = (float4*)(out + base);
      ov[0] = o0; ov[1] = o1;
    }
  }
}

// ---------------------------------------------------------------------------
extern "C" void kernel_launch(void* const* d_in, const int* in_sizes, int n_in,
                              void* d_out, int out_size, void* d_ws, size_t ws_size,
                              hipStream_t stream){
  (void)in_sizes; (void)n_in; (void)out_size; (void)ws_size;
  const float* local       = (const float*)d_in[0];
  const float* pair        = (const float*)d_in[1];
  const float* pair_update = (const float*)d_in[2];
  const int*   neighbours  = (const int*)d_in[3];
  const int*   mask        = (const int*)d_in[4];
  const float* Wa          = (const float*)d_in[5];
  const float* Wb          = (const float*)d_in[6];
  const float* ln_g        = (const float*)d_in[7];
  const float* ln_b        = (const float*)d_in[8];
  const float* W_aug       = (const float*)d_in[9];
  const float* W_lin       = (const float*)d_in[10];
  const float* W_left      = (const float*)d_in[11];
  const float* b_left      = (const float*)d_in[12];
  const float* W_right     = (const float*)d_in[13];
  const float* b_right     = (const float*)d_in[14];
  const float* W1          = (const float*)d_in[15];
  const float* W2          = (const float*)d_in[16];
  const float* W_int       = (const float*)d_in[17];
  const float* b_int       = (const float*)d_in[18];

  float* ws    = (float*)d_ws;
  float* A     = ws;                   // 65536 f32
  float* B     = ws + 65536;           // 65536
  float* inter = ws + 131072;          // 65536
  float* r1023 = ws + 196608;          // 1024
  int*   qpart = (int*)(ws + 197632);  // 32 ints

  k0<<<dim3(Nn), dim3(64), 0, stream>>>(local, Wa, Wb, W_int, b_int, A, B, inter);
  k1<<<dim3(1), dim3(256), 0, stream>>>(pair, pair_update, neighbours, mask,
                                        ln_g, ln_b, W_aug, W_right, b_right,
                                        A, B, r1023, qpart);
  kbig<<<dim3(Nn), dim3(256), 0, stream>>>(pair, pair_update, neighbours,
                                           ln_g, ln_b, W_aug, W_lin,
                                           W_left, b_left, W1, W2,
                                           A, B, inter, r1023, qpart,
                                           (float*)d_out);
}